// Round 1
// 229.850 us; speedup vs baseline: 1.1261x; 1.1261x over previous
//
#include <hip/hip_runtime.h>
#include <math.h>

typedef __bf16 bf16x8 __attribute__((ext_vector_type(8)));
typedef __bf16 bf16x4 __attribute__((ext_vector_type(4)));
typedef float  floatx4 __attribute__((ext_vector_type(4)));
typedef float  floatx2 __attribute__((ext_vector_type(2)));

#define AS1(p) ((__attribute__((address_space(1))) void*)(p))
#define AS3(p) ((__attribute__((address_space(3))) void*)(p))

#define MASKV (-1.0e30f)
#define SOFTMAX_SCALE_LOG2 0.1803368801111244f   // 0.125 * log2(e)
#define ROPE_LOG2F 0.4152410118609203f           // log2(10000)/32

// raw barrier (no vmcnt drain, unlike __syncthreads) + compile-time sched fence
#define BARRIER do { __builtin_amdgcn_sched_barrier(0); \
                     __builtin_amdgcn_s_barrier(); \
                     __builtin_amdgcn_sched_barrier(0); } while (0)

// ---------------------------------------------------------------------------
// One-shot fp32 -> bf16 conversion of x/qkv/wo + rope cos/sin table build.
// ---------------------------------------------------------------------------
__global__ __launch_bounds__(256)
void cvt3_kernel(const float* __restrict__ x, const float* __restrict__ qkv,
                 const float* __restrict__ wo, __bf16* __restrict__ xb,
                 __bf16* __restrict__ qkvb, __bf16* __restrict__ wob,
                 float* __restrict__ rt)
{
    const int bi = blockIdx.x;
    if (bi >= 12288) {
        const int e0 = (bi - 12288) * 1024 + threadIdx.x * 4;
#pragma unroll
        for (int j = 0; j < 4; ++j) {
            const int e = e0 + j;
            const int s = e >> 5, d = e & 31;
            const float f = exp2f(-(float)d * ROPE_LOG2F);
            float sn, cs;
            sincosf((float)s * f, &sn, &cs);
            floatx2 t; t[0] = cs; t[1] = sn;
            *(floatx2*)(rt + e * 2) = t;
        }
        return;
    }
    const float* src;
    __bf16* dst;
    int base;
    if (bi < 8192)       { src = x;   dst = xb;   base = bi * 1024; }
    else if (bi < 11264) { src = qkv; dst = qkvb; base = (bi - 8192) * 1024; }
    else                 { src = wo;  dst = wob;  base = (bi - 11264) * 1024; }

    const int i = base + threadIdx.x * 4;
    const floatx4 v = *(const floatx4*)(src + i);
    bf16x4 o;
    o[0] = (__bf16)v[0]; o[1] = (__bf16)v[1];
    o[2] = (__bf16)v[2]; o[3] = (__bf16)v[3];
    *(bf16x4*)(dst + i) = o;
}

// ---------------------------------------------------------------------------
// Pipelined 128x256 GEMM core (C = A[128xK] * BT[256xK]^T tile), K=1024, BK=64.
// 512 threads = 8 waves (2M x 4N). Per-wave 64x64 output as 4x4 16x16 frags,
// interleaved across halves:
//   rows: (f>>1)*64 + wr*32 + (f&1)*16      (A halves = rows 0..63 / 64..127)
//   cols: wc*64 + g*16                       (wave owns one 64-col span)
// LDS 96 KiB dynamic: 2 bufs x {A0,A1: 4096 elems; B0,B1: 8192 elems}.
// XOR swizzle byte^=(row&7)<<4 on the 128B rows -> conflict-free ds_read_b128;
// inverse swizzle applied to the GLOBAL source addr since global_load_lds
// writes linearly (wave-uniform base + lane*16).
// Schedule (m201 8-phase reconstruction), per K-tile j (buf P=j&1), 4 phases:
//   p1: read A0-frags(8)+B0-frags(4); stage B1(j+1)->buf 1-P; bar; MFMA q(0,0)
//   p2: read B1-frags(4);             stage A0(j+2)->buf P;   bar; MFMA q(0,2)
//   p3: read A1-frags(8);             stage B0(j+2)->buf P;   bar; MFMA q(2,2)
//   p4: (B0 held in regs)             stage A1(j+2)->buf P;   bar; MFMA q(2,0)
//       then s_waitcnt vmcnt(4)  [= the 4 in-flight loads of tile j+2; this
//       completes B1(j+1), so tile j+1 is fully resident]; bar.
// Region safety: each region's last read-phase < its stage-phase, and stages
// only land after the previous phase's post-MFMA barrier (reads drained by
// the data-dep lgkmcnt before that phase's MFMA). vmcnt never drains to 0
// mid-loop (T4). Loads/tile = 6 (B:2 + A:1 + B:2 + A:1).
// ---------------------------------------------------------------------------
__device__ __forceinline__ void gemm_pipe(const __bf16* __restrict__ Ap,
                                          const __bf16* __restrict__ Bp,
                                          const int m0, const int n0,
                                          __bf16* smem, floatx4 (&acc)[4][4])
{
    const int tid  = threadIdx.x;
    const int wave = tid >> 6;
    const int lane = tid & 63;
    const int quad = lane >> 4;
    const int l16  = lane & 15;
    const int wr   = wave >> 2;
    const int wc   = wave & 3;

    const int arow = wr * 32 + l16;          // + f*16 per A-frag (within half)
    const int brow = (wc & 1) * 64 + l16;    // + g*16 per B-frag (within half)
    const int bsel = (wc >> 1) * 8192;       // this wave's B half-region
    const int swz  = (l16 & 7) << 4;         // read-side XOR swizzle (bytes)
    int coff[2];                             // k-step col offsets (elems)
    coff[0] = (( (quad << 4))        ^ swz) >> 1;
    coff[1] = ((64 | (quad << 4))    ^ swz) >> 1;

    auto stageA = [&](int buf, int h, int k0) {          // 1 load/thread (8KB)
        const int o = tid << 4;                          // linear byte offset
        const int r = o >> 7;                            // 0..63
        const int c = (o & 127) ^ ((r & 7) << 4);        // inverse-swizzled col
        const __bf16* src = Ap + (size_t)(m0 + h * 64 + r) * 1024 + k0 + (c >> 1);
        __builtin_amdgcn_global_load_lds(AS1(src),
            AS3(smem + buf * 24576 + h * 4096 + wave * 512), 16, 0, 0);
    };
    auto stageB = [&](int buf, int h, int k0) {          // 2 loads/thread (16KB)
#pragma unroll
        for (int q = 0; q < 2; ++q) {
            const int o = (q * 512 + tid) << 4;
            const int r = o >> 7;                        // 0..127
            const int c = (o & 127) ^ ((r & 7) << 4);
            const __bf16* src = Bp + (size_t)(n0 + h * 128 + r) * 1024 + k0 + (c >> 1);
            __builtin_amdgcn_global_load_lds(AS1(src),
                AS3(smem + buf * 24576 + 8192 + h * 8192 + (q * 8 + wave) * 512), 16, 0, 0);
        }
    };

#define RDA(P, qm, fm, ks) (*(const bf16x8*)(smem + (P) * 24576 + (qm) * 4096 \
                             + ((arow + (fm) * 16) << 6) + coff[ks]))
#define RDB(P, g, ks)      (*(const bf16x8*)(smem + (P) * 24576 + 8192 + bsel \
                             + ((brow + (g) * 16) << 6) + coff[ks]))
#define MFMA8(MB, NB, AV, BV) do { \
    _Pragma("unroll") for (int fm_ = 0; fm_ < 2; ++fm_) \
    _Pragma("unroll") for (int gi_ = 0; gi_ < 2; ++gi_) \
    _Pragma("unroll") for (int ks_ = 0; ks_ < 2; ++ks_) \
        acc[(MB) + fm_][(NB) + gi_] = __builtin_amdgcn_mfma_f32_16x16x32_bf16( \
            AV[fm_][ks_], BV[gi_][ks_], acc[(MB) + fm_][(NB) + gi_], 0, 0, 0); \
} while (0)

    // prologue: tile0 fully + tile1 {A0,B0,A1}; leave tile1's 4 loads in flight
    stageA(0, 0, 0);  stageB(0, 0, 0);  stageA(0, 1, 0);  stageB(0, 1, 0);
    stageA(1, 0, 64); stageB(1, 0, 64); stageA(1, 1, 64);
    asm volatile("s_waitcnt vmcnt(4)" ::: "memory");
    BARRIER;

    bf16x8 a0[2][2], a1[2][2], b0[2][2], b1[2][2];

#define TILE(JT, P) do { \
    const int kn_ = ((JT) + 2) * 64; \
    /* ---- p1: A0 + B0 frags; stage B1(j+1) into idle buffer ---- */ \
    _Pragma("unroll") for (int f_ = 0; f_ < 2; ++f_) \
    _Pragma("unroll") for (int k_ = 0; k_ < 2; ++k_) a0[f_][k_] = RDA(P, 0, f_, k_); \
    _Pragma("unroll") for (int g_ = 0; g_ < 2; ++g_) \
    _Pragma("unroll") for (int k_ = 0; k_ < 2; ++k_) b0[g_][k_] = RDB(P, g_, k_); \
    if ((JT) + 1 < 16) stageB(1 - (P), 1, ((JT) + 1) * 64); \
    BARRIER; \
    __builtin_amdgcn_s_setprio(1); MFMA8(0, 0, a0, b0); __builtin_amdgcn_s_setprio(0); \
    BARRIER; \
    /* ---- p2: B1 frags; stage A0(j+2) (A0 last read at p1) ---- */ \
    _Pragma("unroll") for (int g_ = 0; g_ < 2; ++g_) \
    _Pragma("unroll") for (int k_ = 0; k_ < 2; ++k_) b1[g_][k_] = RDB(P, 2 + g_, k_); \
    if ((JT) + 2 < 16) stageA(P, 0, kn_); \
    BARRIER; \
    __builtin_amdgcn_s_setprio(1); MFMA8(0, 2, a0, b1); __builtin_amdgcn_s_setprio(0); \
    BARRIER; \
    /* ---- p3: A1 frags; stage B0(j+2) (B0 reads ended at p2) ---- */ \
    _Pragma("unroll") for (int f_ = 0; f_ < 2; ++f_) \
    _Pragma("unroll") for (int k_ = 0; k_ < 2; ++k_) a1[f_][k_] = RDA(P, 1, f_, k_); \
    if ((JT) + 2 < 16) stageB(P, 0, kn_); \
    BARRIER; \
    __builtin_amdgcn_s_setprio(1); MFMA8(2, 2, a1, b1); __builtin_amdgcn_s_setprio(0); \
    BARRIER; \
    /* ---- p4: B0 held in regs; stage A1(j+2) (A1 last read at p3) ---- */ \
    if ((JT) + 2 < 16) stageA(P, 1, kn_); \
    BARRIER; \
    __builtin_amdgcn_s_setprio(1); MFMA8(2, 0, a1, b0); __builtin_amdgcn_s_setprio(0); \
    /* counted end-of-tile wait: leaves exactly tile j+2's 4 loads in flight */ \
    if ((JT) + 2 < 16)      { asm volatile("s_waitcnt vmcnt(4)" ::: "memory"); } \
    else if ((JT) + 1 < 16) { asm volatile("s_waitcnt vmcnt(0)" ::: "memory"); } \
    BARRIER; \
} while (0)

    for (int it = 0; it < 8; ++it) {
        TILE(2 * it, 0);
        TILE(2 * it + 1, 1);
    }
#undef TILE
#undef RDA
#undef RDB
#undef MFMA8
}

// ---------------------------------------------------------------------------
// GEMM1 + fused RoPE (table-based) + head-major scatter, pipelined core.
// Wave's 64-col span = one head; rotate-half pairs (d, d+32) are
// acc[f][g] / acc[f][g+2] in the same lane.
// ---------------------------------------------------------------------------
__global__ __launch_bounds__(512, 2)
void gemm_rope_kernel(const __bf16* __restrict__ A, const __bf16* __restrict__ BT,
                      __bf16* __restrict__ Qr, __bf16* __restrict__ Kr,
                      __bf16* __restrict__ Vt, const float* __restrict__ rt)
{
    extern __shared__ __align__(16) __bf16 smem[];
    const int id  = blockIdx.x;              // 768 = 64 m-tiles x 12 n-tiles
    const int xcd = id & 7, lid = id >> 3;   // bijective XCD swizzle (768%8==0)
    const int tm  = xcd * 8 + lid / 12;      // 8x12 tile chunk per XCD
    const int tn  = lid % 12;
    const int m0  = tm * 128, n0 = tn * 256;

    floatx4 acc[4][4] = {};
    gemm_pipe(A, BT, m0, n0, smem, acc);

    const int tid  = threadIdx.x;
    const int wave = tid >> 6;
    const int lane = tid & 63;
    const int quad = lane >> 4, l16 = lane & 15;
    const int wr   = wave >> 2, wc = wave & 3;

    const int gn0    = n0 + wc * 64;          // 64-aligned -> one head
    const int region = gn0 >> 10;             // 0=Q, 1=K, 2=V
    const int h      = (gn0 >> 6) & 15;

    if (region == 2) {
        // V: Vt[(b*16+h)*64 + d][s], 4 consecutive s per lane -> 8B stores
#pragma unroll
        for (int f = 0; f < 4; ++f) {
            const int gm = m0 + (f >> 1) * 64 + wr * 32 + (f & 1) * 16 + quad * 4;
            const int b = gm >> 11, s = gm & 2047;
#pragma unroll
            for (int g = 0; g < 4; ++g) {
                const int d = g * 16 + l16;
                bf16x4 w;
#pragma unroll
                for (int r = 0; r < 4; ++r) w[r] = (__bf16)acc[f][g][r];
                *(bf16x4*)(Vt + ((size_t)(b * 16 + h) * 64 + d) * 2048 + s) = w;
            }
        }
    } else {
        __bf16* dst = region ? Kr : Qr;
#pragma unroll
        for (int g = 0; g < 2; ++g) {
            const int d1 = g * 16 + l16;                  // 0..31
#pragma unroll
            for (int f = 0; f < 4; ++f) {
                const int gm0 = m0 + (f >> 1) * 64 + wr * 32 + (f & 1) * 16 + quad * 4;
                const int b = gm0 >> 11, s0 = gm0 & 2047;
#pragma unroll
                for (int r = 0; r < 4; ++r) {
                    const floatx2 t = *(const floatx2*)(rt + ((s0 + r) * 32 + d1) * 2);
                    const float a1 = acc[f][g][r];
                    const float a2 = acc[f][g + 2][r];
                    __bf16* row = dst + ((size_t)((b * 16 + h) * 2048 + s0 + r)) * 64;
                    row[d1]      = (__bf16)(a1 * t[0] - a2 * t[1]);
                    row[d1 + 32] = (__bf16)(a2 * t[0] + a1 * t[1]);
                }
            }
        }
    }
}

// ---------------------------------------------------------------------------
// GEMM2: out[8192][1024] = ctx[8192][1024] * wob[1024][1024]^T, pipelined core.
// Grid = 256 blocks = exactly one round on 256 CUs.
// ---------------------------------------------------------------------------
__global__ __launch_bounds__(512, 2)
void gemm_bt_kernel(const __bf16* __restrict__ A, const __bf16* __restrict__ BT,
                    float* __restrict__ C)
{
    extern __shared__ __align__(16) __bf16 smem[];
    const int id  = blockIdx.x;              // 256 = 64 m-tiles x 4 n-tiles
    const int xcd = id & 7, lid = id >> 3;
    const int tm  = xcd * 8 + (lid >> 2);
    const int tn  = lid & 3;
    const int m0  = tm * 128, n0 = tn * 256;

    floatx4 acc[4][4] = {};
    gemm_pipe(A, BT, m0, n0, smem, acc);

    const int tid  = threadIdx.x;
    const int wave = tid >> 6, lane = tid & 63;
    const int quad = lane >> 4, l16 = lane & 15;
    const int wr   = wave >> 2, wc = wave & 3;

#pragma unroll
    for (int f = 0; f < 4; ++f) {
        const int row = m0 + (f >> 1) * 64 + wr * 32 + (f & 1) * 16 + quad * 4;
#pragma unroll
        for (int g = 0; g < 4; ++g) {
            const int col = n0 + wc * 64 + g * 16 + l16;
#pragma unroll
            for (int r = 0; r < 4; ++r)
                C[(size_t)(row + r) * 1024 + col] = acc[f][g][r];
        }
    }
}

// ---------------------------------------------------------------------------
// Causal flash attention v6 — cooperative LDS staging (unchanged).
// ---------------------------------------------------------------------------
__global__ __launch_bounds__(256, 4)
void attn_kernel(const __bf16* __restrict__ Qr, const __bf16* __restrict__ Kr,
                 const __bf16* __restrict__ Vt, __bf16* __restrict__ ctx)
{
    __shared__ __align__(16) __bf16 Ks[64 * 64];
    __shared__ __align__(16) __bf16 Vs[64 * 64];
    __shared__ __align__(16) __bf16 plds[4][16 * 72];

    const int bh   = blockIdx.x;
    const int b    = bh >> 4, h = bh & 15;
    const int tid  = threadIdx.x;
    const int wave = tid >> 6;
    const int lane = tid & 63;
    const int quad = lane >> 4, l16 = lane & 15;
    const int sw   = l16 & 7;

    const __bf16* Qb = Qr + (size_t)bh * 2048 * 64;
    const __bf16* Kb = Kr + (size_t)bh * 2048 * 64;
    const __bf16* Vb = Vt + (size_t)bh * 64 * 2048;
    __bf16* Pw = &plds[wave][0];

    const int c0   = tid;
    const int row0 = c0 >> 3, jg0 = (c0 & 7) ^ (row0 & 7);
    const int c1   = 256 + tid;
    const int row1 = c1 >> 3, jg1 = (c1 & 7) ^ (row1 & 7);

    const int tiles[2] = { (int)blockIdx.y, 31 - (int)blockIdx.y };

    for (int pass = 0; pass < 2; ++pass) {
        const int q0b  = tiles[pass] * 64;
        const int q0   = q0b + wave * 16;
        const int qa   = q0 + l16;
        const int kend = q0b + 64;

        bf16x8 bq[2];
#pragma unroll
        for (int t = 0; t < 2; ++t)
            bq[t] = *(const bf16x8*)(Qb + (q0 + l16) * 64 + t * 32 + quad * 8);

        floatx4 o[4] = {};
        float lpart = 0.f;

        for (int kt = 0; kt < kend; kt += 64) {
            __builtin_amdgcn_global_load_lds(AS1(Kb + (size_t)(kt + row0) * 64 + jg0 * 8),
                                             AS3(Ks + wave * 512), 16, 0, 0);
            __builtin_amdgcn_global_load_lds(AS1(Vb + (size_t)row0 * 2048 + kt + jg0 * 8),
                                             AS3(Vs + wave * 512), 16, 0, 0);
            __builtin_amdgcn_global_load_lds(AS1(Kb + (size_t)(kt + row1) * 64 + jg1 * 8),
                                             AS3(Ks + (4 + wave) * 512), 16, 0, 0);
            __builtin_amdgcn_global_load_lds(AS1(Vb + (size_t)row1 * 2048 + kt + jg1 * 8),
                                             AS3(Vs + (4 + wave) * 512), 16, 0, 0);
            asm volatile("s_waitcnt vmcnt(0)" ::: "memory");
            __syncthreads();

            floatx4 s[4] = {};
#pragma unroll
            for (int st = 0; st < 4; ++st) {
                bf16x8 ka0 = *(const bf16x8*)(Ks + (st * 16 + l16) * 64 + ((0 + quad) ^ sw) * 8);
                bf16x8 ka1 = *(const bf16x8*)(Ks + (st * 16 + l16) * 64 + ((4 + quad) ^ sw) * 8);
                s[st] = __builtin_amdgcn_mfma_f32_16x16x32_bf16(ka0, bq[0], s[st], 0, 0, 0);
                s[st] = __builtin_amdgcn_mfma_f32_16x16x32_bf16(ka1, bq[1], s[st], 0, 0, 0);
            }

#pragma unroll
            for (int st = 0; st < 4; ++st) {
                bf16x4 w;
#pragma unroll
                for (int r = 0; r < 4; ++r) {
                    const int key = kt + st * 16 + quad * 4 + r;
                    const float v = (key > qa) ? MASKV : s[st][r] * SOFTMAX_SCALE_LOG2;
                    const float p = __builtin_amdgcn_exp2f(v);
                    lpart += p;
                    w[r] = (__bf16)p;
                }
                *(bf16x4*)(Pw + l16 * 72 + st * 16 + quad * 4) = w;
            }

            asm volatile("s_waitcnt lgkmcnt(0)" ::: "memory");
            bf16x8 ap0 = *(const bf16x8*)(Pw + l16 * 72 + quad * 8);
            bf16x8 ap1 = *(const bf16x8*)(Pw + l16 * 72 + 32 + quad * 8);

#pragma unroll
            for (int nt = 0; nt < 4; ++nt) {
                bf16x8 bv0 = *(const bf16x8*)(Vs + (nt * 16 + l16) * 64 + ((0 + quad) ^ sw) * 8);
                bf16x8 bv1 = *(const bf16x8*)(Vs + (nt * 16 + l16) * 64 + ((4 + quad) ^ sw) * 8);
                o[nt] = __builtin_amdgcn_mfma_f32_16x16x32_bf16(ap0, bv0, o[nt], 0, 0, 0);
                o[nt] = __builtin_amdgcn_mfma_f32_16x16x32_bf16(ap1, bv1, o[nt], 0, 0, 0);
            }

            __syncthreads();
        }

        float l = lpart;
        l += __shfl_xor(l, 16, 64);
        l += __shfl_xor(l, 32, 64);
        float lr[4];
#pragma unroll
        for (int r = 0; r < 4; ++r)
            lr[r] = __shfl(l, quad * 4 + r, 64);
#pragma unroll
        for (int nt = 0; nt < 4; ++nt)
#pragma unroll
            for (int r = 0; r < 4; ++r) {
                const int srow = q0 + quad * 4 + r;
                const float inv_l = 1.0f / fmaxf(lr[r], 1e-20f);
                ctx[((size_t)(b * 2048 + srow)) * 1024 + h * 64 + nt * 16 + l16] =
                    (__bf16)(o[nt][r] * inv_l);
            }
    }
}

// ---------------------------------------------------------------------------
// Workspace layout (88.5 MiB):
//   xb   [ 0M..16M)   qkvb [16M..22M)   wob [22M..24M)
//   Qr   [24M..40M)   Kr   [40M..56M)   Vt  [56M..72M)   ctx [72M..88M)
//   rt   [88M..88.5M) rope cos/sin table (2048 x 32 float2)
// ---------------------------------------------------------------------------
extern "C" void kernel_launch(void* const* d_in, const int* in_sizes, int n_in,
                              void* d_out, int out_size, void* d_ws, size_t ws_size,
                              hipStream_t stream)
{
    const float* x   = (const float*)d_in[0];   // [4,2048,1024] fp32
    const float* qkv = (const float*)d_in[1];   // [3072,1024]   fp32 (N x K)
    const float* wo  = (const float*)d_in[2];   // [1024,1024]   fp32 (N x K)
    float* out = (float*)d_out;                 // [8192,1024]   fp32

    char* ws = (char*)d_ws;
    const size_t MB = 1024 * 1024;
    __bf16* xb   = (__bf16*)(ws);
    __bf16* qkvb = (__bf16*)(ws + 16 * MB);
    __bf16* wob  = (__bf16*)(ws + 22 * MB);
    __bf16* Qr   = (__bf16*)(ws + 24 * MB);
    __bf16* Kr   = (__bf16*)(ws + 40 * MB);
    __bf16* Vt   = (__bf16*)(ws + 56 * MB);
    __bf16* ctx  = (__bf16*)(ws + 72 * MB);
    float*  rt   = (float*) (ws + 88 * MB);

    // 96 KiB dynamic LDS (> 64 KiB default) for the pipelined GEMMs
    hipFuncSetAttribute((const void*)gemm_rope_kernel,
                        hipFuncAttributeMaxDynamicSharedMemorySize, 98304);
    hipFuncSetAttribute((const void*)gemm_bt_kernel,
                        hipFuncAttributeMaxDynamicSharedMemorySize, 98304);

    // 0) conversions + rope table in one launch
    cvt3_kernel<<<12352, 256, 0, stream>>>(x, qkv, wo, xb, qkvb, wob, rt);
    // 1) QKV projection, 8-phase pipelined, fused table-RoPE + scatter
    gemm_rope_kernel<<<768, 512, 98304, stream>>>(xb, qkvb, Qr, Kr, Vt, rt);
    // 2) causal flash attention -> ctx (bf16)
    attn_kernel<<<dim3(64, 16), 256, 0, stream>>>(Qr, Kr, Vt, ctx);
    // 3) output projection, pipelined -> fp32 out
    gemm_bt_kernel<<<256, 512, 98304, stream>>>(ctx, wob, out);
}